// Round 8
// baseline (187.196 us; speedup 1.0000x reference)
//
#include <hip/hip_runtime.h>

typedef unsigned short u16;
typedef unsigned int u32;
typedef __attribute__((ext_vector_type(8))) short bf16x8;
typedef __attribute__((ext_vector_type(4))) float f32x4;
typedef __attribute__((ext_vector_type(4))) u32 u32x4;
typedef __attribute__((ext_vector_type(2))) u32 u32x2;

__device__ __forceinline__ u16 f2bf(float f) {
  u32 u = __builtin_bit_cast(u32, f);
  return (u16)((u + 0x7FFFu + ((u >> 16) & 1u)) >> 16);
}
__device__ __forceinline__ float bf2f(u16 b) {
  return __builtin_bit_cast(float, (u32)b << 16);
}
// pack two floats to adjacent bf16 (RNE), x in low half
__device__ __forceinline__ u32 packbf2(float x, float y) {
  u32 ux = __builtin_bit_cast(u32, x);
  ux += 0x7FFFu + ((ux >> 16) & 1u);
  u32 uy = __builtin_bit_cast(u32, y);
  uy += 0x7FFFu + ((uy >> 16) & 1u);
  return __builtin_amdgcn_perm(uy, ux, 0x07060302u);
}

__device__ __forceinline__ float fexp2(float x) {
#if __has_builtin(__builtin_amdgcn_exp2f)
  return __builtin_amdgcn_exp2f(x);
#else
  return __expf(x * 0.6931471805599453f);
#endif
}

__device__ __forceinline__ void lds_async16(const void* g, void* l) {
  auto gp = reinterpret_cast<const __attribute__((address_space(1))) u32*>(
      reinterpret_cast<uintptr_t>(g));
  auto lp = reinterpret_cast<__attribute__((address_space(3))) u32*>(
      reinterpret_cast<uintptr_t>(l));
  __builtin_amdgcn_global_load_lds(gp, lp, 16, 0, 0);
}

// two small weight converts in one launch (block 192 is exactly the boundary)
__global__ void cvt2_kernel(const float* __restrict__ a, const float* __restrict__ b,
                            u16* __restrict__ oa, u16* __restrict__ ob, int na4, int nb4) {
  int i = blockIdx.x * 256 + threadIdx.x;
  const float* src;
  u16* dst;
  int idx;
  if (i < na4) {
    src = a; dst = oa; idx = i;
  } else {
    idx = i - na4;
    if (idx >= nb4) return;
    src = b; dst = ob;
  }
  f32x4 v = *(const f32x4*)(src + (size_t)idx * 4);
  u32x2 o;
  o[0] = packbf2(v[0], v[1]);
  o[1] = packbf2(v[2], v[3]);
  *(u32x2*)(dst + (size_t)idx * 4) = o;
}

// ---------------- qkv GEMM with fused fp32->bf16 A staging ----------------
// C[m][n] = sum_k X[m][k]*B[n][k] + bias[n].  X: 33792 x 256 fp32.
// B: 768 x 256 bf16. C: bf16. A staged via reg-loads + RNE pack + ds_write_b128
// (global_load_lds can't convert). N-tile-fast block order for x LLC locality.
// MFMA core + epilogue byte-identical to the proven r4 gemm (do NOT swap
// mfma operand order — r5/r6 failed on that).
__global__ __launch_bounds__(256) void gemm_qkv_kernel(
    const float* __restrict__ X, const u16* __restrict__ B,
    const float* __restrict__ bias, u16* __restrict__ C) {
  const int N = 768, K = 256;
  __shared__ u16 sA[128 * 32];
  __shared__ u16 sB[128 * 32];
  const int tid = threadIdx.x;
  const int bid = blockIdx.x;
  const int m0 = (bid / 6) * 128;
  const int n0 = (bid % 6) * 128;
  const int w = tid >> 6;
  const int lane = tid & 63;
  const int wr = (w >> 1) * 64;
  const int wc = (w & 1) * 64;
  const int lm = lane & 15;
  const int lk = (lane >> 4) * 8;

  f32x4 acc[4][4] = {};

  const int srow = tid >> 2;
  const int ssub = (tid & 3) * 8;
  const float* Ag0 = X + (size_t)(m0 + srow) * K + ssub;
  const float* Ag1 = Ag0 + (size_t)64 * K;
  const u16* Bg = B + (size_t)(n0 + srow) * K + ssub;
  const size_t rstep = (size_t)64 * K;

  for (int k0 = 0; k0 < K; k0 += 32) {
    __syncthreads();
    lds_async16(Bg + k0, &sB[tid * 8]);
    lds_async16(Bg + rstep + k0, &sB[2048 + tid * 8]);
    {
      f32x4 a0 = *(const f32x4*)(Ag0 + k0);
      f32x4 a1 = *(const f32x4*)(Ag0 + k0 + 4);
      f32x4 c0 = *(const f32x4*)(Ag1 + k0);
      f32x4 c1 = *(const f32x4*)(Ag1 + k0 + 4);
      u32x4 pa, pc;
      pa[0] = packbf2(a0[0], a0[1]); pa[1] = packbf2(a0[2], a0[3]);
      pa[2] = packbf2(a1[0], a1[1]); pa[3] = packbf2(a1[2], a1[3]);
      pc[0] = packbf2(c0[0], c0[1]); pc[1] = packbf2(c0[2], c0[3]);
      pc[2] = packbf2(c1[0], c1[1]); pc[3] = packbf2(c1[2], c1[3]);
      *(u32x4*)&sA[tid * 8] = pa;
      *(u32x4*)&sA[2048 + tid * 8] = pc;
    }
    __syncthreads();
    bf16x8 af[4], bfr[4];
#pragma unroll
    for (int i = 0; i < 4; ++i)
      af[i] = *(const bf16x8*)&sA[(wr + i * 16 + lm) * 32 + lk];
#pragma unroll
    for (int j = 0; j < 4; ++j)
      bfr[j] = *(const bf16x8*)&sB[(wc + j * 16 + lm) * 32 + lk];
#pragma unroll
    for (int i = 0; i < 4; ++i)
#pragma unroll
      for (int j = 0; j < 4; ++j)
        acc[i][j] = __builtin_amdgcn_mfma_f32_16x16x32_bf16(af[i], bfr[j], acc[i][j], 0, 0, 0);
  }

  const int r0 = (lane >> 4) * 4;
#pragma unroll
  for (int j = 0; j < 4; ++j) {
    const int n = n0 + wc + j * 16 + lm;
    const float bv = bias[n];
#pragma unroll
    for (int i = 0; i < 4; ++i) {
#pragma unroll
      for (int r = 0; r < 4; ++r) {
        const int m = m0 + wr + i * 16 + r0 + r;
        C[(size_t)m * N + n] = f2bf(acc[i][j][r] + bv);
      }
    }
  }
}

// ---------------- output GEMM with fused overlap-add combine ----------------
// y[m][n] = sum_k oc[m][k]*B[n][k] + bias[n], where oc[m] = avg of the 1-2
// ows blocks covering global row m (overlap-add / cnt; identical numerics to
// the old combine kernel: fp32 avg of bf16 + RNE repack). y: fp32.
__global__ __launch_bounds__(256) void gemm_out_kernel(
    const u16* __restrict__ OWS, const u16* __restrict__ B,
    const float* __restrict__ bias, float* __restrict__ C) {
  const int N = 256, K = 256;
  __shared__ u16 sA[128 * 32];
  __shared__ u16 sB[128 * 32];
  const int tid = threadIdx.x;
  const int bid = blockIdx.x;
  const int m0 = (bid >> 1) * 128;
  const int n0 = (bid & 1) * 128;
  const int w = tid >> 6;
  const int lane = tid & 63;
  const int wr = (w >> 1) * 64;
  const int wc = (w & 1) * 64;
  const int lm = lane & 15;
  const int lk = (lane >> 4) * 8;

  f32x4 acc[4][4] = {};

  const int srow = tid >> 2;
  const int ssub = (tid & 3) * 8;
  const u16* Bg = B + (size_t)(n0 + srow) * K + ssub;
  const size_t rstep = (size_t)64 * K;

  // per-half source pointers for the covering ows blocks (hoisted out of K-loop);
  // when only one block covers, both pointers alias it: (a+a)*0.5 == a exactly.
  const u16* p[2][2];
#pragma unroll
  for (int hh = 0; hh < 2; ++hh) {
    int m = m0 + hh * 64 + srow;
    int bc = m / 4224;
    int t = m - bc * 4224;
    int i0 = t >> 7;
    const u16* q0 = OWS + (((size_t)((bc * 32 + i0) * 256 + (t - (i0 << 7)))) << 8) + ssub;
    const u16* q1 = OWS + (((size_t)((bc * 32 + (i0 - 1)) * 256 + (t - ((i0 - 1) << 7)))) << 8) + ssub;
    p[hh][0] = (i0 <= 31) ? q0 : q1;
    p[hh][1] = (i0 >= 1) ? q1 : q0;
  }

  for (int k0 = 0; k0 < K; k0 += 32) {
    __syncthreads();
    lds_async16(Bg + k0, &sB[tid * 8]);
    lds_async16(Bg + rstep + k0, &sB[2048 + tid * 8]);
#pragma unroll
    for (int hh = 0; hh < 2; ++hh) {
      u32x4 v0 = *(const u32x4*)(p[hh][0] + k0);
      u32x4 v1 = *(const u32x4*)(p[hh][1] + k0);
      u32x4 o;
#pragma unroll
      for (int q = 0; q < 4; ++q) {
        float a0 = bf2f((u16)(v0[q] & 0xFFFFu)), b0 = bf2f((u16)(v1[q] & 0xFFFFu));
        float a1 = bf2f((u16)(v0[q] >> 16)),     b1 = bf2f((u16)(v1[q] >> 16));
        o[q] = packbf2((a0 + b0) * 0.5f, (a1 + b1) * 0.5f);
      }
      *(u32x4*)&sA[hh * 2048 + tid * 8] = o;
    }
    __syncthreads();
    bf16x8 af[4], bfr[4];
#pragma unroll
    for (int i = 0; i < 4; ++i)
      af[i] = *(const bf16x8*)&sA[(wr + i * 16 + lm) * 32 + lk];
#pragma unroll
    for (int j = 0; j < 4; ++j)
      bfr[j] = *(const bf16x8*)&sB[(wc + j * 16 + lm) * 32 + lk];
#pragma unroll
    for (int i = 0; i < 4; ++i)
#pragma unroll
      for (int j = 0; j < 4; ++j)
        acc[i][j] = __builtin_amdgcn_mfma_f32_16x16x32_bf16(af[i], bfr[j], acc[i][j], 0, 0, 0);
  }

  const int r0 = (lane >> 4) * 4;
#pragma unroll
  for (int j = 0; j < 4; ++j) {
    const int n = n0 + wc + j * 16 + lm;
    const float bv = bias[n];
#pragma unroll
    for (int i = 0; i < 4; ++i) {
#pragma unroll
      for (int r = 0; r < 4; ++r) {
        const int m = m0 + wr + i * 16 + r0 + r;
        C[(size_t)m * N + n] = acc[i][j][r] + bv;
      }
    }
  }
}

// ---------------- fused per-(block,head) attention (r7, proven) ----------------
// S^T compute (mfma(K,Q)) so P regs are 4 consecutive j -> b64 LDS writes.
// PV in two 32-row halves; LDS = sVt 16896 + sP 10240 = 27136 B.
// launch_bounds(256,2): (256,4) spilled catastrophically (r2). `#pragma unroll 1`
// on the ch loop is load-bearing: full unroll hoists all kf loads and spills (r3).
__global__ __launch_bounds__(256, 2) void attn_kernel(const u16* __restrict__ qkv,
                                                      u16* __restrict__ o_ws) {
  __shared__ u16 sVt[32 * 264];   // V transposed, stride 264 u16 (528B)
  __shared__ u16 sP[4 * 32 * 40]; // per-wave P half-tile: 32 rows x 40 u16

  const int bid = blockIdx.x;
  const int n = bid >> 3;
  const int h = bid & 7;
  const int rowbase = (n >> 5) * 4224 + (n & 31) * 128;
  const int tid = threadIdx.x;
  const int w = tid >> 6;
  const int lane = tid & 63;
  const int lm = lane & 15;
  const int lg = lane >> 4;

  // stage V transposed for this head
#pragma unroll
  for (int it = 0; it < 4; ++it) {
    int c = it * 256 + tid;
    int row = c >> 2;
    int sub = (c & 3) * 8;
    const u16* gv = qkv + (size_t)(rowbase + row) * 768 + 512 + h * 32 + sub;
    u32x4 vv = *(const u32x4*)gv;
#pragma unroll
    for (int q = 0; q < 4; ++q) {
      sVt[(sub + 2 * q) * 264 + row] = (u16)(vv[q] & 0xFFFFu);
      sVt[(sub + 2 * q + 1) * 264 + row] = (u16)(vv[q] >> 16);
    }
  }

  // Q fragments straight from global (wave-private rows; 16 rows x 64B contiguous)
  bf16x8 qf[4];
#pragma unroll
  for (int rt = 0; rt < 4; ++rt) {
    int row = rowbase + w * 64 + rt * 16 + lm;
    qf[rt] = *(const bf16x8*)(qkv + (size_t)row * 768 + h * 32 + lg * 8);
  }

  __syncthreads();

  f32x4 oacc[4][2] = {};
  float lsum[4] = {0.f, 0.f, 0.f, 0.f};
  u16* myP = sP + w * (32 * 40);
  const float C1 = 0.25500035370494726f; // scale * log2(e)
  const float C2 = 1.4426950408889634f;  // log2(e)
  const int jq = lg * 4;
  const u16* kbase = qkv + (size_t)(rowbase + lm) * 768 + 256 + h * 32 + lg * 8;
  const int D0w = w * 64;

#pragma unroll 1
  for (int ch = 0; ch < 8; ++ch) {
    bf16x8 kf[2], vf[2];
#pragma unroll
    for (int ct = 0; ct < 2; ++ct)
      kf[ct] = *(const bf16x8*)(kbase + (size_t)(ch * 32 + ct * 16) * 768);
#pragma unroll
    for (int ctd = 0; ctd < 2; ++ctd)
      vf[ctd] = *(const bf16x8*)&sVt[(ctd * 16 + lm) * 264 + ch * 32 + lg * 8];

#pragma unroll
    for (int hf = 0; hf < 2; ++hf) {
#pragma unroll
      for (int ct = 0; ct < 2; ++ct) {
#pragma unroll
        for (int rl = 0; rl < 2; ++rl) {
          const int rt = hf * 2 + rl;
          f32x4 s = __builtin_amdgcn_mfma_f32_16x16x32_bf16(kf[ct], qf[rt], f32x4{0.f, 0.f, 0.f, 0.f}, 0, 0, 0);
          const int D0 = D0w + rt * 16 - (ch * 32 + ct * 16); // wave-uniform
          float p0, p1, p2, p3;
          if (D0 >= 16 && D0 <= 112) {        // fully in-band: +1 bias
            p0 = fexp2(__builtin_fmaf(s[0], C1, C2));
            p1 = fexp2(__builtin_fmaf(s[1], C1, C2));
            p2 = fexp2(__builtin_fmaf(s[2], C1, C2));
            p3 = fexp2(__builtin_fmaf(s[3], C1, C2));
          } else if (D0 == 0) {               // diagonal: in-band iff lm >= jq+r
            p0 = fexp2(__builtin_fmaf(s[0], C1, (lm >= jq + 0) ? C2 : 0.0f));
            p1 = fexp2(__builtin_fmaf(s[1], C1, (lm >= jq + 1) ? C2 : 0.0f));
            p2 = fexp2(__builtin_fmaf(s[2], C1, (lm >= jq + 2) ? C2 : 0.0f));
            p3 = fexp2(__builtin_fmaf(s[3], C1, (lm >= jq + 3) ? C2 : 0.0f));
          } else if (D0 == 128) {             // far edge: in-band iff lm < jq+r
            p0 = fexp2(__builtin_fmaf(s[0], C1, (lm < jq + 0) ? C2 : 0.0f));
            p1 = fexp2(__builtin_fmaf(s[1], C1, (lm < jq + 1) ? C2 : 0.0f));
            p2 = fexp2(__builtin_fmaf(s[2], C1, (lm < jq + 2) ? C2 : 0.0f));
            p3 = fexp2(__builtin_fmaf(s[3], C1, (lm < jq + 3) ? C2 : 0.0f));
          } else {                            // fully out of band: no bias
            p0 = fexp2(s[0] * C1);
            p1 = fexp2(s[1] * C1);
            p2 = fexp2(s[2] * C1);
            p3 = fexp2(s[3] * C1);
          }
          lsum[rt] += (p0 + p1) + (p2 + p3);
          u32 u0 = __builtin_bit_cast(u32, p0) + 0x8000u;
          u32 u1 = __builtin_bit_cast(u32, p1) + 0x8000u;
          u32 u2 = __builtin_bit_cast(u32, p2) + 0x8000u;
          u32 u3 = __builtin_bit_cast(u32, p3) + 0x8000u;
          u32x2 pk;
          pk[0] = __builtin_amdgcn_perm(u1, u0, 0x07060302u);
          pk[1] = __builtin_amdgcn_perm(u3, u2, 0x07060302u);
          *(u32x2*)&myP[(rl * 16 + lm) * 40 + ct * 16 + jq] = pk;
        }
      }
      // O(half) += P(half) * Vc (wave-private P: in-order LDS per wave)
      bf16x8 pf[2];
#pragma unroll
      for (int rl = 0; rl < 2; ++rl)
        pf[rl] = *(const bf16x8*)&myP[(rl * 16 + lm) * 40 + lg * 8];
      // pin WAR order: these reads must precede the next half's overwrites
      __asm__ __volatile__("" ::: "memory");
#pragma unroll
      for (int rl = 0; rl < 2; ++rl)
#pragma unroll
        for (int ctd = 0; ctd < 2; ++ctd)
          oacc[hf * 2 + rl][ctd] =
              __builtin_amdgcn_mfma_f32_16x16x32_bf16(pf[rl], vf[ctd], oacc[hf * 2 + rl][ctd], 0, 0, 0);
    }
  }

  // softmax denominators: reduce across the 4 quads (lanes lm, lm+16, lm+32, lm+48)
  float linv[4];
#pragma unroll
  for (int rt = 0; rt < 4; ++rt) {
    float v = lsum[rt];
    v += __shfl_xor(v, 16);
    v += __shfl_xor(v, 32);
    linv[rt] = 1.0f / v;
  }

  // normalize + store; O C-layout rows are i = rt*16 + lg*4 + r -> shfl the inverse
#pragma unroll
  for (int rt = 0; rt < 4; ++rt) {
#pragma unroll
    for (int r = 0; r < 4; ++r) {
      float inv = __shfl(linv[rt], jq + r);
      int i_g = w * 64 + rt * 16 + jq + r;
#pragma unroll
      for (int ctd = 0; ctd < 2; ++ctd) {
        float v = oacc[rt][ctd][r] * inv;
        u32 u = __builtin_bit_cast(u32, v) + 0x8000u;
        o_ws[((size_t)(n * 256 + i_g)) * 256 + h * 32 + ctd * 16 + lm] = (u16)(u >> 16);
      }
    }
  }
}

extern "C" void kernel_launch(void* const* d_in, const int* in_sizes, int n_in,
                              void* d_out, int out_size, void* d_ws, size_t ws_size,
                              hipStream_t stream) {
  const float* x = (const float*)d_in[0];
  const float* w_in = (const float*)d_in[1];
  const float* b_in = (const float*)d_in[2];
  const float* w_out = (const float*)d_in[3];
  const float* b_out = (const float*)d_in[4];
  float* y = (float*)d_out;
  char* ws = (char*)d_ws;

  // workspace layout (bytes)
  u16* qkv = (u16*)(ws);                  // 33792*768*2   = 51,904,512
  u16* ows = (u16*)(ws + 51904512);       // 256*256*256*2 = 33,554,432
  u16* winb = (u16*)(ws + 85458944);      // 768*256*2     = 393,216
  u16* woutb = (u16*)(ws + 85852160);     // 256*256*2     = 131,072  (end 85,983,232)

  cvt2_kernel<<<256, 256, 0, stream>>>(w_in, w_out, winb, woutb, 49152, 16384);

  // qkv = x @ w_in^T + b_in (fused fp32->bf16 A staging; once per row)
  gemm_qkv_kernel<<<1584, 256, 0, stream>>>(x, winb, b_in, qkv);

  // per-(block, head) attention
  attn_kernel<<<2048, 256, 0, stream>>>(qkv, ows);

  // y = overlap_avg(ows) @ w_out^T + b_out (combine fused into A staging)
  gemm_out_kernel<<<528, 256, 0, stream>>>(ows, woutb, b_out, y);
}